// Round 14
// baseline (251.974 us; speedup 1.0000x reference)
//
#include <hip/hip_runtime.h>

// Problem constants (B,T,C,NH fixed by the reference).
constexpr int kB  = 8;
constexpr int kT  = 1024;
constexpr int kC  = 768;
constexpr int kNH = 12;
constexpr int kHD = 64;          // C/NH
constexpr int kM  = kB * kT;     // 8192 rows
constexpr int k3C = 3 * kC;      // 2304
constexpr int kQK = 2 * kC;      // 1536: qkv2 row stride (Q,K only; V -> VT)

using bf16x8 = __attribute__((ext_vector_type(8))) __bf16;
using f32x4  = __attribute__((ext_vector_type(4))) float;

// fp32 -> bf16 round-to-nearest-even.
__device__ __forceinline__ unsigned short f2bf(float f) {
    union { float f; unsigned int u; } v; v.f = f;
    unsigned int r = v.u + 0x7fffu + ((v.u >> 16) & 1u);
    return (unsigned short)(r >> 16);
}

// Async global->LDS, 16 B/lane (wave-uniform LDS base; HW scatters lane i
// at base + i*16 — m104/m108).
__device__ __forceinline__ void async16(const void* g, void* l) {
    __builtin_amdgcn_global_load_lds(
        (__attribute__((address_space(1))) void*)g,
        (__attribute__((address_space(3))) void*)l, 16, 0, 0);
}

// s_waitcnt imm: exp=7, lgkm=15 (no wait), vmcnt=N -> 0x0F70|N.
template<int IMM> __device__ __forceinline__ void wait_vm() {
    __builtin_amdgcn_s_waitcnt(IMM);
}
__device__ __forceinline__ void wait_vm0() { __builtin_amdgcn_s_waitcnt(0x0F70); }

// ---------------- pre-passes ----------------

// fp32 -> bf16 elementwise (n divisible by 4*256).
__global__ __launch_bounds__(256) void cvt_bf16_kernel(
    const float* __restrict__ in, unsigned short* __restrict__ out)
{
    const int i = blockIdx.x * 256 + threadIdx.x;
    const float4 v = ((const float4*)in)[i];
    ushort4 o;
    o.x = f2bf(v.x); o.y = f2bf(v.y); o.z = f2bf(v.z); o.w = f2bf(v.w);
    ((ushort4*)out)[i] = o;
}

// W[K][N] fp32 -> Wt[N][K] bf16.  Grid (N/32, K/32), block 256 (32x8).
__global__ __launch_bounds__(256) void transpose_cvt_kernel(
    const float* __restrict__ W, unsigned short* __restrict__ Wt, int K, int N)
{
    __shared__ float tile[32][33];
    const int tx = threadIdx.x & 31, ty = threadIdx.x >> 5;
    const int n0 = blockIdx.x * 32, k0 = blockIdx.y * 32;
    #pragma unroll
    for (int i = 0; i < 4; ++i)
        tile[ty + i * 8][tx] = W[(size_t)(k0 + ty + i * 8) * N + n0 + tx];
    __syncthreads();
    #pragma unroll
    for (int i = 0; i < 4; ++i)
        Wt[(size_t)(n0 + ty + i * 8) * K + k0 + tx] = f2bf(tile[tx][ty + i * 8]);
}

// ---------------- MFMA GEMM (3-stage pipelined K-loop) ----------------
// Round-13 structure, unchanged (gemm1 plateaued at ~70 µs / 410 TF, on the
// m97 shape-curve for K=768; five structural variants r9-r13 converge here).
// MODE 1 (gemm1): bf16 out; n<1536 -> qkv2 (stride 1536); n>=1536 is V,
// written transposed to VT[bh][d][t].  MODE 0: fp32 out (gemm2).
template<int NSUB, int MODE, int K>
__global__ __launch_bounds__(256) void gemm_mfma_kernel(
    const unsigned short* __restrict__ A,      // [M][K] bf16
    const unsigned short* __restrict__ Bt,     // [N][K] bf16
    const float* __restrict__ bias,
    void* __restrict__ outv,
    unsigned short* __restrict__ vt,           // MODE 1 only
    int N)
{
    constexpr int NW = NSUB / 2;
    constexpr int BB = (NSUB / 4 > 0) ? NSUB / 4 : 1;
    constexpr int P  = 2 + BB;
    constexpr int WAIT_P = 0x0F70 | P;
    constexpr int NITER = K / 32;

    alignas(16) __shared__ unsigned short As[3][8 * 512];
    alignas(16) __shared__ unsigned short Bs[3][NSUB * 512];

    const int tid  = threadIdx.x;
    const int w    = tid >> 6;
    const int lane = tid & 63;
    const int wr = w >> 1, wc = w & 1;
    const int m0 = blockIdx.x * 128;             // m fastest (L2 locality)
    const int n0 = blockIdx.y * (NSUB * 16);

    const int fr = lane & 15;
    const int fk = (lane >> 4) * 8;

    auto stage = [&](int bufi, int kt) {
        #pragma unroll
        for (int t = 0; t < 2; ++t) {
            const int fa = w * 2 + t;
            const unsigned short* ga =
                A + (size_t)(m0 + fa * 16 + fr) * K + kt + fk;
            async16(ga, &As[bufi][fa * 512]);
        }
        #pragma unroll
        for (int t = 0; t < BB; ++t) {
            const int fb = w * BB + t;
            const unsigned short* gb =
                Bt + (size_t)(n0 + fb * 16 + fr) * K + kt + fk;
            async16(gb, &Bs[bufi][fb * 512]);
        }
    };

    f32x4 acc[4][NW];
    #pragma unroll
    for (int i = 0; i < 4; ++i)
        #pragma unroll
        for (int j = 0; j < NW; ++j) {
            f32x4 z = {0.f, 0.f, 0.f, 0.f};
            acc[i][j] = z;
        }

    stage(0, 0);
    stage(1, 32);
    for (int it3 = 0; it3 < NITER; it3 += 3) {
        #pragma unroll
        for (int u = 0; u < 3; ++u) {            // cur = u, pf = (u+2)%3
            const int it = it3 + u;
            if (it + 1 < NITER) wait_vm<WAIT_P>();
            else                wait_vm<0x0F70>();
            __builtin_amdgcn_s_barrier();
            if (it + 2 < NITER) stage((u + 2) % 3, (it + 2) * 32);

            bf16x8 a[4], b[NW];
            #pragma unroll
            for (int i = 0; i < 4; ++i)
                a[i] = *(const bf16x8*)&As[u][(wr * 4 + i) * 512 + lane * 8];
            #pragma unroll
            for (int j = 0; j < NW; ++j)
                b[j] = *(const bf16x8*)&Bs[u][(wc * NW + j) * 512 + lane * 8];
            #pragma unroll
            for (int i = 0; i < 4; ++i)
                #pragma unroll
                for (int j = 0; j < NW; ++j)
                    acc[i][j] = __builtin_amdgcn_mfma_f32_16x16x32_bf16(
                        a[i], b[j], acc[i][j], 0, 0, 0);
        }
    }

    const int quad  = lane >> 4;
    const int col16 = lane & 15;
    float biasv[NW];
    #pragma unroll
    for (int j = 0; j < NW; ++j)
        biasv[j] = bias[n0 + wc * (NW * 16) + j * 16 + col16];

    if (MODE == 1 && n0 >= kQK) {
        const int bidx = m0 >> 10;
        #pragma unroll
        for (int i = 0; i < 4; ++i) {
            const int t = (m0 + wr * 64 + i * 16 + quad * 4) & 1023;
            #pragma unroll
            for (int j = 0; j < NW; ++j) {
                const int hv = n0 + wc * (NW * 16) + j * 16 + col16 - kQK;
                const int h = hv >> 6, d = hv & 63;
                ushort4 o;
                o.x = f2bf(acc[i][j][0] + biasv[j]);
                o.y = f2bf(acc[i][j][1] + biasv[j]);
                o.z = f2bf(acc[i][j][2] + biasv[j]);
                o.w = f2bf(acc[i][j][3] + biasv[j]);
                *(ushort4*)&vt[((size_t)(bidx * kNH + h) * kHD + d) * kT + t] = o;
            }
        }
    } else {
        #pragma unroll
        for (int i = 0; i < 4; ++i) {
            #pragma unroll
            for (int r = 0; r < 4; ++r) {
                const int row = m0 + wr * 64 + i * 16 + quad * 4 + r;
                #pragma unroll
                for (int j = 0; j < NW; ++j) {
                    const int col = n0 + wc * (NW * 16) + j * 16 + col16;
                    const float v = acc[i][j][r] + biasv[j];
                    if (MODE == 1)
                        ((unsigned short*)outv)[(size_t)row * kQK + col] = f2bf(v);
                    else
                        ((float*)outv)[(size_t)row * N + col] = v;
                }
            }
        }
    }
}

// ---------- MFMA flash attention (shared-prefix paired q-tiles) ----------
// Round-14: tile B's key range (chunks 0..pid) is a SUBSET of tile A's
// (0..15-pid), so each key chunk is staged ONCE and both q-tiles compute
// on the shared prefix: stagings/barriers per block 17 -> 16-pid (avg
// 12.5, -26%), K/V DMA -26%, chunk-computes unchanged (17).  Also the
// softmax denominator is kept as a PER-LANE PARTIAL (alpha is row-uniform
// from the max-reduce alone) and reduced once in the epilogue: shfl count
// per chunk halves (32 -> 16; shfl = ds_permute = LDS pipe).
__global__ __launch_bounds__(256) void attn_mfma_kernel(
    const unsigned short* __restrict__ qkv2,
    const unsigned short* __restrict__ VT,     // [96][64][1024]
    unsigned short* __restrict__ y)            // [8192][768]
{
    alignas(16) __shared__ unsigned short Kf[2][8 * 512];  // 16 KB
    alignas(16) __shared__ unsigned short Vf[2][8 * 512];  // 16 KB
    alignas(16) __shared__ unsigned short Pf[8 * 512];     // 8 KB, wave-private

    const int tid  = threadIdx.x;
    const int w    = tid >> 6;
    const int lane = tid & 63;
    const int quad = lane >> 4, l15 = lane & 15;
    const int bh  = blockIdx.x >> 3;
    const int b   = bh / kNH, h = bh % kNH;
    const int pid = blockIdx.x & 7;
    const int t0A = (15 - pid) * 64;     // heavy tile
    const int t0B = pid * 64;            // light tile (range subset of A's)
    const int nch = 16 - pid;            // staged chunks: 0..15-pid

    auto stage = [&](int bufi, int kbase) {
        const unsigned short* gk = qkv2 +
            (size_t)(b * kT + kbase + w * 16 + l15) * kQK + kC + h * kHD + quad * 8;
        async16(gk,      &Kf[bufi][(w * 2 + 0) * 512]);
        async16(gk + 32, &Kf[bufi][(w * 2 + 1) * 512]);
        const unsigned short* gv = VT +
            ((size_t)bh * kHD + w * 16 + l15) * kT + kbase + quad * 8;
        async16(gv,      &Vf[bufi][(w * 2 + 0) * 512]);
        async16(gv + 32, &Vf[bufi][(w * 2 + 1) * 512]);
    };

    // Stage chunk 0; load both tiles' Q via Pf (wave-private) -> registers.
    stage(0, 0);
    bf16x8 aqA0, aqA1, aqB0, aqB1;
    {
        const unsigned short* gA = qkv2 +
            (size_t)(b * kT + t0A + w * 16 + l15) * kQK + h * kHD + quad * 8;
        async16(gA,      &Pf[(w * 2 + 0) * 512]);
        async16(gA + 32, &Pf[(w * 2 + 1) * 512]);
        wait_vm0();
        aqA0 = *(const bf16x8*)&Pf[(w * 2 + 0) * 512 + lane * 8];
        aqA1 = *(const bf16x8*)&Pf[(w * 2 + 1) * 512 + lane * 8];
        const unsigned short* gB = qkv2 +
            (size_t)(b * kT + t0B + w * 16 + l15) * kQK + h * kHD + quad * 8;
        async16(gB,      &Pf[(w * 2 + 0) * 512]);
        async16(gB + 32, &Pf[(w * 2 + 1) * 512]);
        wait_vm0();
        aqB0 = *(const bf16x8*)&Pf[(w * 2 + 0) * 512 + lane * 8];
        aqB1 = *(const bf16x8*)&Pf[(w * 2 + 1) * 512 + lane * 8];
    }

    float mA[4], lA[4], mB[4], lB[4];
    f32x4 oA[4], oB[4];
    #pragma unroll
    for (int r = 0; r < 4; ++r) {
        mA[r] = -INFINITY; lA[r] = 0.f;
        mB[r] = -INFINITY; lB[r] = 0.f;
    }
    #pragma unroll
    for (int n = 0; n < 4; ++n) {
        f32x4 z = {0.f, 0.f, 0.f, 0.f};
        oA[n] = z; oB[n] = z;
    }

    // One staged chunk -> compute tile A always, tile B on the shared prefix.
    auto chunk_compute = [&](const bf16x8& q0, const bf16x8& q1,
                             float* m_run, float* l_run, f32x4* acc_o,
                             int t0, int kbase, int buf, bool diag) {
        // S = Q K^T; 8 MFMAs.
        f32x4 acc_s[4];
        #pragma unroll
        for (int k = 0; k < 4; ++k) {
            f32x4 z = {0.f, 0.f, 0.f, 0.f};
            acc_s[k] = z;
        }
        #pragma unroll
        for (int ksub = 0; ksub < 4; ++ksub) {
            const bf16x8 bk0 =
                *(const bf16x8*)&Kf[buf][(ksub * 2 + 0) * 512 + lane * 8];
            const bf16x8 bk1 =
                *(const bf16x8*)&Kf[buf][(ksub * 2 + 1) * 512 + lane * 8];
            acc_s[ksub] = __builtin_amdgcn_mfma_f32_16x16x32_bf16(
                q0, bk0, acc_s[ksub], 0, 0, 0);
            acc_s[ksub] = __builtin_amdgcn_mfma_f32_16x16x32_bf16(
                q1, bk1, acc_s[ksub], 0, 0, 0);
        }

        float sv[4][4];   // [ksub][r]
        #pragma unroll
        for (int ksub = 0; ksub < 4; ++ksub)
            #pragma unroll
            for (int r = 0; r < 4; ++r)
                sv[ksub][r] = acc_s[ksub][r] * 0.125f;
        if (diag) {
            const int qrow = t0 + w * 16 + quad * 4;   // + r
            #pragma unroll
            for (int ksub = 0; ksub < 4; ++ksub) {
                const int key = kbase + ksub * 16 + l15;
                #pragma unroll
                for (int r = 0; r < 4; ++r)
                    if (key > qrow + r) sv[ksub][r] = -INFINITY;
            }
        }

        // Online softmax: max-reduce (4 shfl/row); l kept per-lane partial.
        float alpha[4];
        #pragma unroll
        for (int r = 0; r < 4; ++r) {
            float mx = fmaxf(fmaxf(sv[0][r], sv[1][r]),
                             fmaxf(sv[2][r], sv[3][r]));
            mx = fmaxf(mx, __shfl_xor(mx, 1));
            mx = fmaxf(mx, __shfl_xor(mx, 2));
            mx = fmaxf(mx, __shfl_xor(mx, 4));
            mx = fmaxf(mx, __shfl_xor(mx, 8));
            const float m_new = fmaxf(m_run[r], mx);
            alpha[r] = __expf(m_run[r] - m_new);   // 1st chunk: exp(-inf)=0
            float ps = 0.f;
            #pragma unroll
            for (int ksub = 0; ksub < 4; ++ksub) {
                sv[ksub][r] = __expf(sv[ksub][r] - m_new);
                ps += sv[ksub][r];
            }
            l_run[r] = l_run[r] * alpha[r] + ps;   // per-lane partial sum
            m_run[r] = m_new;
        }

        // Scatter P into wave-private A-frag layout (same-wave DS ordering).
        #pragma unroll
        for (int ksub = 0; ksub < 4; ++ksub) {
            const int key = ksub * 16 + l15;
            #pragma unroll
            for (int r = 0; r < 4; ++r) {
                const int lp = quad * 4 + r + ((key & 31) >> 3) * 16;
                Pf[(w * 2 + (key >> 5)) * 512 + lp * 8 + (key & 7)] =
                    f2bf(sv[ksub][r]);
            }
        }

        // O = O*alpha + P V; 8 MFMAs.
        #pragma unroll
        for (int n = 0; n < 4; ++n)
            #pragma unroll
            for (int r = 0; r < 4; ++r)
                acc_o[n][r] *= alpha[r];
        const bf16x8 ap0 = *(const bf16x8*)&Pf[(w * 2 + 0) * 512 + lane * 8];
        const bf16x8 ap1 = *(const bf16x8*)&Pf[(w * 2 + 1) * 512 + lane * 8];
        #pragma unroll
        for (int nsub = 0; nsub < 4; ++nsub) {
            const bf16x8 bv0 =
                *(const bf16x8*)&Vf[buf][(nsub * 2 + 0) * 512 + lane * 8];
            const bf16x8 bv1 =
                *(const bf16x8*)&Vf[buf][(nsub * 2 + 1) * 512 + lane * 8];
            acc_o[nsub] = __builtin_amdgcn_mfma_f32_16x16x32_bf16(
                ap0, bv0, acc_o[nsub], 0, 0, 0);
            acc_o[nsub] = __builtin_amdgcn_mfma_f32_16x16x32_bf16(
                ap1, bv1, acc_o[nsub], 0, 0, 0);
        }
    };

    for (int c = 0; c < nch; ++c) {
        const int kbase = c * 64;
        const int buf = c & 1;
        wait_vm0();        // drain stage(c) (issued prev iter / preloop)
        __syncthreads();   // all waves' parts visible; prev buffer free
        if (c + 1 < nch) stage(1 - buf, kbase + 64);  // prefetch

        chunk_compute(aqA0, aqA1, mA, lA, oA, t0A, kbase, buf, kbase == t0A);
        if (c <= pid)
            chunk_compute(aqB0, aqB1, mB, lB, oB, t0B, kbase, buf, kbase == t0B);
    }

    // Epilogue: reduce the per-lane l partials once, then write y.
    auto write_tile = [&](float* l_run, f32x4* acc_o, int t0) {
        float inv[4];
        #pragma unroll
        for (int r = 0; r < 4; ++r) {
            float s = l_run[r];
            s += __shfl_xor(s, 1);
            s += __shfl_xor(s, 2);
            s += __shfl_xor(s, 4);
            s += __shfl_xor(s, 8);
            inv[r] = 1.0f / s;
        }
        #pragma unroll
        for (int nsub = 0; nsub < 4; ++nsub)
            #pragma unroll
            for (int r = 0; r < 4; ++r)
                y[(size_t)(b * kT + t0 + w * 16 + quad * 4 + r) * kC +
                  h * kHD + nsub * 16 + l15] = f2bf(acc_o[nsub][r] * inv[r]);
    };
    write_tile(lA, oA, t0A);
    write_tile(lB, oB, t0B);
}

extern "C" void kernel_launch(void* const* d_in, const int* in_sizes, int n_in,
                              void* d_out, int out_size, void* d_ws, size_t ws_size,
                              hipStream_t stream) {
    const float* x      = (const float*)d_in[0];
    const float* w_attn = (const float*)d_in[1];
    const float* b_attn = (const float*)d_in[2];
    const float* w_proj = (const float*)d_in[3];
    const float* b_proj = (const float*)d_in[4];
    float* out = (float*)d_out;

    // Workspace (bf16, ~67.6 MiB):
    unsigned short* xb     = (unsigned short*)d_ws;           // [8192][768]
    unsigned short* wattnT = xb     + (size_t)kM * kC;        // [2304][768]
    unsigned short* wprojT = wattnT + (size_t)k3C * kC;       // [768][768]
    unsigned short* qkv2   = wprojT + (size_t)kC * kC;        // [8192][1536]
    unsigned short* VT     = qkv2   + (size_t)kM * kQK;       // [96][64][1024]
    unsigned short* yb     = VT     + (size_t)kNH * kB * kHD * kT; // [8192][768]

    // Pre-passes: cast x; transpose+cast weights to [N][K].
    cvt_bf16_kernel<<<(kM * kC) / (4 * 256), 256, 0, stream>>>(x, xb);
    transpose_cvt_kernel<<<dim3(k3C / 32, kC / 32), 256, 0, stream>>>(
        w_attn, wattnT, kC, k3C);
    transpose_cvt_kernel<<<dim3(kC / 32, kC / 32), 256, 0, stream>>>(
        w_proj, wprojT, kC, kC);

    // 1) QKV projection: Q,K -> qkv2 (stride 1536); V -> VT (fused
    //    transpose).  Grid (m=64, n=18), m fastest for L2 locality.
    gemm_mfma_kernel<8, 1, kC><<<dim3(kM / 128, k3C / 128), 256, 0, stream>>>(
        xb, wattnT, b_attn, qkv2, VT, k3C);

    // 2) MFMA causal attention (shared-prefix paired q-tiles) -> yb
    attn_mfma_kernel<<<kB * kNH * 8, 256, 0, stream>>>(qkv2, VT, yb);

    // 3) Output projection: yb @ wprojT^T + b_proj -> out (fp32).
    //    Grid (m=64, n=12), m fastest.
    gemm_mfma_kernel<4, 0, kC><<<dim3(kM / 128, kC / 64), 256, 0, stream>>>(
        yb, wprojT, b_proj, out, nullptr, kC);
}

// Round 15
// 227.714 us; speedup vs baseline: 1.1065x; 1.1065x over previous
//
#include <hip/hip_runtime.h>

// Problem constants (B,T,C,NH fixed by the reference).
constexpr int kB  = 8;
constexpr int kT  = 1024;
constexpr int kC  = 768;
constexpr int kNH = 12;
constexpr int kHD = 64;          // C/NH
constexpr int kM  = kB * kT;     // 8192 rows
constexpr int k3C = 3 * kC;      // 2304
constexpr int kQK = 2 * kC;      // 1536: qkv2 row stride (Q,K only; V -> VT)

using bf16x8 = __attribute__((ext_vector_type(8))) __bf16;
using f32x4  = __attribute__((ext_vector_type(4))) float;

// fp32 -> bf16 round-to-nearest-even.
__device__ __forceinline__ unsigned short f2bf(float f) {
    union { float f; unsigned int u; } v; v.f = f;
    unsigned int r = v.u + 0x7fffu + ((v.u >> 16) & 1u);
    return (unsigned short)(r >> 16);
}

// Async global->LDS, 16 B/lane (wave-uniform LDS base; HW scatters lane i
// at base + i*16 — m104/m108).
__device__ __forceinline__ void async16(const void* g, void* l) {
    __builtin_amdgcn_global_load_lds(
        (__attribute__((address_space(1))) void*)g,
        (__attribute__((address_space(3))) void*)l, 16, 0, 0);
}

// s_waitcnt imm: exp=7, lgkm=15 (no wait), vmcnt=N -> 0x0F70|N.
template<int IMM> __device__ __forceinline__ void wait_vm() {
    __builtin_amdgcn_s_waitcnt(IMM);
}
__device__ __forceinline__ void wait_vm0() { __builtin_amdgcn_s_waitcnt(0x0F70); }

// ---------------- pre-passes ----------------

// fp32 -> bf16 elementwise (n divisible by 4*256).
__global__ __launch_bounds__(256) void cvt_bf16_kernel(
    const float* __restrict__ in, unsigned short* __restrict__ out)
{
    const int i = blockIdx.x * 256 + threadIdx.x;
    const float4 v = ((const float4*)in)[i];
    ushort4 o;
    o.x = f2bf(v.x); o.y = f2bf(v.y); o.z = f2bf(v.z); o.w = f2bf(v.w);
    ((ushort4*)out)[i] = o;
}

// W[K][N] fp32 -> Wt[N][K] bf16.  Grid (N/32, K/32), block 256 (32x8).
__global__ __launch_bounds__(256) void transpose_cvt_kernel(
    const float* __restrict__ W, unsigned short* __restrict__ Wt, int K, int N)
{
    __shared__ float tile[32][33];
    const int tx = threadIdx.x & 31, ty = threadIdx.x >> 5;
    const int n0 = blockIdx.x * 32, k0 = blockIdx.y * 32;
    #pragma unroll
    for (int i = 0; i < 4; ++i)
        tile[ty + i * 8][tx] = W[(size_t)(k0 + ty + i * 8) * N + n0 + tx];
    __syncthreads();
    #pragma unroll
    for (int i = 0; i < 4; ++i)
        Wt[(size_t)(n0 + ty + i * 8) * K + k0 + tx] = f2bf(tile[tx][ty + i * 8]);
}

// ---------------- MFMA GEMM (3-stage pipelined K-loop) ----------------
// Round-13 structure, unchanged (gemm1 plateaued at ~70 µs / 410 TF across
// six structural variants r8-r13; FETCH is near-ideal after the grid swap).
// MODE 1 (gemm1): bf16 out; n<1536 -> qkv2 (stride 1536); n>=1536 is V,
// written transposed to VT[bh][d][t].  MODE 0: fp32 out (gemm2).
template<int NSUB, int MODE, int K>
__global__ __launch_bounds__(256) void gemm_mfma_kernel(
    const unsigned short* __restrict__ A,      // [M][K] bf16
    const unsigned short* __restrict__ Bt,     // [N][K] bf16
    const float* __restrict__ bias,
    void* __restrict__ outv,
    unsigned short* __restrict__ vt,           // MODE 1 only
    int N)
{
    constexpr int NW = NSUB / 2;
    constexpr int BB = (NSUB / 4 > 0) ? NSUB / 4 : 1;
    constexpr int P  = 2 + BB;
    constexpr int WAIT_P = 0x0F70 | P;
    constexpr int NITER = K / 32;

    alignas(16) __shared__ unsigned short As[3][8 * 512];
    alignas(16) __shared__ unsigned short Bs[3][NSUB * 512];

    const int tid  = threadIdx.x;
    const int w    = tid >> 6;
    const int lane = tid & 63;
    const int wr = w >> 1, wc = w & 1;
    const int m0 = blockIdx.x * 128;             // m fastest (L2 locality)
    const int n0 = blockIdx.y * (NSUB * 16);

    const int fr = lane & 15;
    const int fk = (lane >> 4) * 8;

    auto stage = [&](int bufi, int kt) {
        #pragma unroll
        for (int t = 0; t < 2; ++t) {
            const int fa = w * 2 + t;
            const unsigned short* ga =
                A + (size_t)(m0 + fa * 16 + fr) * K + kt + fk;
            async16(ga, &As[bufi][fa * 512]);
        }
        #pragma unroll
        for (int t = 0; t < BB; ++t) {
            const int fb = w * BB + t;
            const unsigned short* gb =
                Bt + (size_t)(n0 + fb * 16 + fr) * K + kt + fk;
            async16(gb, &Bs[bufi][fb * 512]);
        }
    };

    f32x4 acc[4][NW];
    #pragma unroll
    for (int i = 0; i < 4; ++i)
        #pragma unroll
        for (int j = 0; j < NW; ++j) {
            f32x4 z = {0.f, 0.f, 0.f, 0.f};
            acc[i][j] = z;
        }

    stage(0, 0);
    stage(1, 32);
    for (int it3 = 0; it3 < NITER; it3 += 3) {
        #pragma unroll
        for (int u = 0; u < 3; ++u) {            // cur = u, pf = (u+2)%3
            const int it = it3 + u;
            if (it + 1 < NITER) wait_vm<WAIT_P>();
            else                wait_vm<0x0F70>();
            __builtin_amdgcn_s_barrier();
            if (it + 2 < NITER) stage((u + 2) % 3, (it + 2) * 32);

            bf16x8 a[4], b[NW];
            #pragma unroll
            for (int i = 0; i < 4; ++i)
                a[i] = *(const bf16x8*)&As[u][(wr * 4 + i) * 512 + lane * 8];
            #pragma unroll
            for (int j = 0; j < NW; ++j)
                b[j] = *(const bf16x8*)&Bs[u][(wc * NW + j) * 512 + lane * 8];
            #pragma unroll
            for (int i = 0; i < 4; ++i)
                #pragma unroll
                for (int j = 0; j < NW; ++j)
                    acc[i][j] = __builtin_amdgcn_mfma_f32_16x16x32_bf16(
                        a[i], b[j], acc[i][j], 0, 0, 0);
        }
    }

    const int quad  = lane >> 4;
    const int col16 = lane & 15;
    float biasv[NW];
    #pragma unroll
    for (int j = 0; j < NW; ++j)
        biasv[j] = bias[n0 + wc * (NW * 16) + j * 16 + col16];

    if (MODE == 1 && n0 >= kQK) {
        const int bidx = m0 >> 10;
        #pragma unroll
        for (int i = 0; i < 4; ++i) {
            const int t = (m0 + wr * 64 + i * 16 + quad * 4) & 1023;
            #pragma unroll
            for (int j = 0; j < NW; ++j) {
                const int hv = n0 + wc * (NW * 16) + j * 16 + col16 - kQK;
                const int h = hv >> 6, d = hv & 63;
                ushort4 o;
                o.x = f2bf(acc[i][j][0] + biasv[j]);
                o.y = f2bf(acc[i][j][1] + biasv[j]);
                o.z = f2bf(acc[i][j][2] + biasv[j]);
                o.w = f2bf(acc[i][j][3] + biasv[j]);
                *(ushort4*)&vt[((size_t)(bidx * kNH + h) * kHD + d) * kT + t] = o;
            }
        }
    } else {
        #pragma unroll
        for (int i = 0; i < 4; ++i) {
            #pragma unroll
            for (int r = 0; r < 4; ++r) {
                const int row = m0 + wr * 64 + i * 16 + quad * 4 + r;
                #pragma unroll
                for (int j = 0; j < NW; ++j) {
                    const int col = n0 + wc * (NW * 16) + j * 16 + col16;
                    const float v = acc[i][j][r] + biasv[j];
                    if (MODE == 1)
                        ((unsigned short*)outv)[(size_t)row * kQK + col] = f2bf(v);
                    else
                        ((float*)outv)[(size_t)row * N + col] = v;
                }
            }
        }
    }
}

// ---------------- MFMA flash attention (paired q-tiles) ----------------
// Round-15 = round-13 structure REVERTED (round-14's shared-prefix pairing
// doubled live register state: VGPR 76->100, occupancy 19->15%, attn 60->75
// µs — falsified).  One register-neutral cut kept from r14: the softmax
// denominator stays a PER-LANE PARTIAL (alpha needs only the max-reduce)
// and is reduced once per phase in the epilogue — removes 16 shfl
// (= ds_permute, LDS pipe) per chunk for +8 at the end.
__global__ __launch_bounds__(256) void attn_mfma_kernel(
    const unsigned short* __restrict__ qkv2,
    const unsigned short* __restrict__ VT,     // [96][64][1024]
    unsigned short* __restrict__ y)            // [8192][768]
{
    alignas(16) __shared__ unsigned short Kf[2][8 * 512];  // 16 KB
    alignas(16) __shared__ unsigned short Vf[2][8 * 512];  // 16 KB
    alignas(16) __shared__ unsigned short Pf[8 * 512];     // 8 KB, wave-private

    const int tid  = threadIdx.x;
    const int w    = tid >> 6;
    const int lane = tid & 63;
    const int quad = lane >> 4, l15 = lane & 15;
    const int bh  = blockIdx.x >> 3;
    const int b   = bh / kNH, h = bh % kNH;
    const int pid = blockIdx.x & 7;

    auto stage = [&](int bufi, int kbase) {
        const unsigned short* gk = qkv2 +
            (size_t)(b * kT + kbase + w * 16 + l15) * kQK + kC + h * kHD + quad * 8;
        async16(gk,      &Kf[bufi][(w * 2 + 0) * 512]);
        async16(gk + 32, &Kf[bufi][(w * 2 + 1) * 512]);
        const unsigned short* gv = VT +
            ((size_t)bh * kHD + w * 16 + l15) * kT + kbase + quad * 8;
        async16(gv,      &Vf[bufi][(w * 2 + 0) * 512]);
        async16(gv + 32, &Vf[bufi][(w * 2 + 1) * 512]);
    };

    #pragma unroll 1
    for (int phase = 0; phase < 2; ++phase) {
        const int t0 = (phase == 0 ? (15 - pid) : pid) * 64;  // heavy first
        const int nchunks = t0 / 64 + 1;

        __syncthreads();   // prev-phase buffer reads complete
        stage(0, 0);
        {
            const unsigned short* g0 = qkv2 +
                (size_t)(b * kT + t0 + w * 16 + l15) * kQK + h * kHD + quad * 8;
            async16(g0,      &Pf[(w * 2 + 0) * 512]);
            async16(g0 + 32, &Pf[(w * 2 + 1) * 512]);
        }
        wait_vm0();   // own-wave DMA drained; Pf region is wave-private
        const bf16x8 aq0 = *(const bf16x8*)&Pf[(w * 2 + 0) * 512 + lane * 8];
        const bf16x8 aq1 = *(const bf16x8*)&Pf[(w * 2 + 1) * 512 + lane * 8];

        float m_run[4], l_run[4];
        f32x4 acc_o[4];
        #pragma unroll
        for (int r = 0; r < 4; ++r) { m_run[r] = -INFINITY; l_run[r] = 0.f; }
        #pragma unroll
        for (int n = 0; n < 4; ++n) {
            f32x4 z = {0.f, 0.f, 0.f, 0.f};
            acc_o[n] = z;
        }

        for (int c = 0; c < nchunks; ++c) {
            const int kbase = c * 64;
            const int buf = c & 1;
            wait_vm0();        // drain stage(c)
            __syncthreads();
            if (c + 1 < nchunks) stage(1 - buf, kbase + 64);  // prefetch

            f32x4 acc_s[4];
            #pragma unroll
            for (int k = 0; k < 4; ++k) {
                f32x4 z = {0.f, 0.f, 0.f, 0.f};
                acc_s[k] = z;
            }
            #pragma unroll
            for (int ksub = 0; ksub < 4; ++ksub) {
                const bf16x8 bk0 =
                    *(const bf16x8*)&Kf[buf][(ksub * 2 + 0) * 512 + lane * 8];
                const bf16x8 bk1 =
                    *(const bf16x8*)&Kf[buf][(ksub * 2 + 1) * 512 + lane * 8];
                acc_s[ksub] = __builtin_amdgcn_mfma_f32_16x16x32_bf16(
                    aq0, bk0, acc_s[ksub], 0, 0, 0);
                acc_s[ksub] = __builtin_amdgcn_mfma_f32_16x16x32_bf16(
                    aq1, bk1, acc_s[ksub], 0, 0, 0);
            }

            float sv[4][4];   // [ksub][r]
            #pragma unroll
            for (int ksub = 0; ksub < 4; ++ksub)
                #pragma unroll
                for (int r = 0; r < 4; ++r)
                    sv[ksub][r] = acc_s[ksub][r] * 0.125f;
            if (kbase == t0) {
                const int qrow = t0 + w * 16 + quad * 4;   // + r
                #pragma unroll
                for (int ksub = 0; ksub < 4; ++ksub) {
                    const int key = kbase + ksub * 16 + l15;
                    #pragma unroll
                    for (int r = 0; r < 4; ++r)
                        if (key > qrow + r) sv[ksub][r] = -INFINITY;
                }
            }

            // Online softmax: max-reduce (4 shfl/row); l per-lane partial
            // (deferred reduction — alpha depends only on the max).
            float alpha[4];
            #pragma unroll
            for (int r = 0; r < 4; ++r) {
                float mx = fmaxf(fmaxf(sv[0][r], sv[1][r]),
                                 fmaxf(sv[2][r], sv[3][r]));
                mx = fmaxf(mx, __shfl_xor(mx, 1));
                mx = fmaxf(mx, __shfl_xor(mx, 2));
                mx = fmaxf(mx, __shfl_xor(mx, 4));
                mx = fmaxf(mx, __shfl_xor(mx, 8));
                const float m_new = fmaxf(m_run[r], mx);
                alpha[r] = __expf(m_run[r] - m_new);  // 1st chunk: exp(-inf)=0
                float ps = 0.f;
                #pragma unroll
                for (int ksub = 0; ksub < 4; ++ksub) {
                    sv[ksub][r] = __expf(sv[ksub][r] - m_new);
                    ps += sv[ksub][r];
                }
                l_run[r] = l_run[r] * alpha[r] + ps;   // per-lane partial
                m_run[r] = m_new;
            }

            #pragma unroll
            for (int ksub = 0; ksub < 4; ++ksub) {
                const int key = ksub * 16 + l15;
                #pragma unroll
                for (int r = 0; r < 4; ++r) {
                    const int lp = quad * 4 + r + ((key & 31) >> 3) * 16;
                    Pf[(w * 2 + (key >> 5)) * 512 + lp * 8 + (key & 7)] =
                        f2bf(sv[ksub][r]);
                }
            }

            #pragma unroll
            for (int n = 0; n < 4; ++n)
                #pragma unroll
                for (int r = 0; r < 4; ++r)
                    acc_o[n][r] *= alpha[r];
            const bf16x8 ap0 = *(const bf16x8*)&Pf[(w * 2 + 0) * 512 + lane * 8];
            const bf16x8 ap1 = *(const bf16x8*)&Pf[(w * 2 + 1) * 512 + lane * 8];
            #pragma unroll
            for (int nsub = 0; nsub < 4; ++nsub) {
                const bf16x8 bv0 =
                    *(const bf16x8*)&Vf[buf][(nsub * 2 + 0) * 512 + lane * 8];
                const bf16x8 bv1 =
                    *(const bf16x8*)&Vf[buf][(nsub * 2 + 1) * 512 + lane * 8];
                acc_o[nsub] = __builtin_amdgcn_mfma_f32_16x16x32_bf16(
                    ap0, bv0, acc_o[nsub], 0, 0, 0);
                acc_o[nsub] = __builtin_amdgcn_mfma_f32_16x16x32_bf16(
                    ap1, bv1, acc_o[nsub], 0, 0, 0);
            }
        }

        // Epilogue: reduce per-lane l partials once, then write y.
        float inv[4];
        #pragma unroll
        for (int r = 0; r < 4; ++r) {
            float s = l_run[r];
            s += __shfl_xor(s, 1);
            s += __shfl_xor(s, 2);
            s += __shfl_xor(s, 4);
            s += __shfl_xor(s, 8);
            inv[r] = 1.0f / s;
        }
        #pragma unroll
        for (int nsub = 0; nsub < 4; ++nsub)
            #pragma unroll
            for (int r = 0; r < 4; ++r)
                y[(size_t)(b * kT + t0 + w * 16 + quad * 4 + r) * kC +
                  h * kHD + nsub * 16 + l15] = f2bf(acc_o[nsub][r] * inv[r]);
    }
}

extern "C" void kernel_launch(void* const* d_in, const int* in_sizes, int n_in,
                              void* d_out, int out_size, void* d_ws, size_t ws_size,
                              hipStream_t stream) {
    const float* x      = (const float*)d_in[0];
    const float* w_attn = (const float*)d_in[1];
    const float* b_attn = (const float*)d_in[2];
    const float* w_proj = (const float*)d_in[3];
    const float* b_proj = (const float*)d_in[4];
    float* out = (float*)d_out;

    // Workspace (bf16, ~67.6 MiB):
    unsigned short* xb     = (unsigned short*)d_ws;           // [8192][768]
    unsigned short* wattnT = xb     + (size_t)kM * kC;        // [2304][768]
    unsigned short* wprojT = wattnT + (size_t)k3C * kC;       // [768][768]
    unsigned short* qkv2   = wprojT + (size_t)kC * kC;        // [8192][1536]
    unsigned short* VT     = qkv2   + (size_t)kM * kQK;       // [96][64][1024]
    unsigned short* yb     = VT     + (size_t)kNH * kB * kHD * kT; // [8192][768]

    // Pre-passes: cast x; transpose+cast weights to [N][K].
    cvt_bf16_kernel<<<(kM * kC) / (4 * 256), 256, 0, stream>>>(x, xb);
    transpose_cvt_kernel<<<dim3(k3C / 32, kC / 32), 256, 0, stream>>>(
        w_attn, wattnT, kC, k3C);
    transpose_cvt_kernel<<<dim3(kC / 32, kC / 32), 256, 0, stream>>>(
        w_proj, wprojT, kC, kC);

    // 1) QKV projection: Q,K -> qkv2 (stride 1536); V -> VT (fused
    //    transpose).  Grid (m=64, n=18), m fastest for L2 locality.
    gemm_mfma_kernel<8, 1, kC><<<dim3(kM / 128, k3C / 128), 256, 0, stream>>>(
        xb, wattnT, b_attn, qkv2, VT, k3C);

    // 2) MFMA causal attention (paired q-tiles, uniform blocks) -> yb
    attn_mfma_kernel<<<kB * kNH * 8, 256, 0, stream>>>(qkv2, VT, yb);

    // 3) Output projection: yb @ wprojT^T + b_proj -> out (fp32).
    //    Grid (m=64, n=12), m fastest.
    gemm_mfma_kernel<4, 0, kC><<<dim3(kM / 128, kC / 64), 256, 0, stream>>>(
        yb, wprojT, b_proj, out, nullptr, kC);
}